// Round 5
// baseline (578.176 us; speedup 1.0000x reference)
//
#include <hip/hip_runtime.h>

#define EE 512
#define SS 128
#define BB 4
#define NH 8
#define HD 64
#define FFD 2048
#define NL 4
#define LDQ 2048   // qkvv concat leading dim; also kproj_all row stride

typedef short bf16x8 __attribute__((ext_vector_type(8)));
typedef float f32x4 __attribute__((ext_vector_type(4)));

__device__ __forceinline__ ushort f2bf(float f) {
    uint u = __float_as_uint(f);
    return (ushort)((u + 0x7fffu + ((u >> 16) & 1u)) >> 16);
}
__device__ __forceinline__ float bflo(uint u) { return __uint_as_float(u << 16); }
__device__ __forceinline__ float bfhi(uint u) { return __uint_as_float(u & 0xffff0000u); }

// async 16B global->LDS. LDS dest = wave-uniform base + lane*16 (HW rule).
__device__ __forceinline__ void gll16(const ushort* g, ushort* l) {
    __builtin_amdgcn_global_load_lds(
        (const __attribute__((address_space(1))) void*)g,
        (__attribute__((address_space(3))) void*)l, 16, 0, 0);
}

// ---------------------------------------------------------------------------
// bf16 MFMA GEMM, 3-buffer depth-2 global_load_lds pipeline, counted vmcnt.
// C[M,N] = A[M,K] @ B[N,K]^T.  BM=32, BN=64, BK=64, 256 thr / 4 waves.
// LDS K-chunk-major: chunk c (16B of K) x row. A chunk 32x16B, B chunk 64x16B.
// Steady state: while computing tile t, tiles t+1,t+2 are in flight;
// end-of-iter s_waitcnt vmcnt(3) retires tile t+1 only (never drain to 0).
// flags: bit0=+bias[col], bit1=relu. resid f32 optional. Cf f32 / Cb bf16.
// ---------------------------------------------------------------------------
struct GemmJob {
    const ushort* A; const ushort* B;
    float* Cf; ushort* Cb;
    const float* bias; const float* resid;
    int M, N, K, flags, nbx, base;
};

__global__ __launch_bounds__(256) void gemm_bf16(GemmJob j0, GemmJob j1, int njobs)
{
    __shared__ ushort As[3][2048];   // 3 x 4KB  (8 chunks x 32 rows x 16B)
    __shared__ ushort Bs[3][4096];   // 3 x 8KB  (8 chunks x 64 rows x 16B)
    GemmJob j = (njobs > 1 && (int)blockIdx.x >= j1.base) ? j1 : j0;
    const int bid = (int)blockIdx.x - j.base;
    const int by = bid / j.nbx, bx = bid % j.nbx;
    const int rowBase = by * 32, colBase = bx * 64;
    const int t = threadIdx.x, lane = t & 63, wid = t >> 6;
    const int wc = wid;                      // wave covers cols wc*16..+15
    const int Kd = j.K, Md = j.M, Nd = j.N;

    const ushort* Bg = j.B + (size_t)(colBase + lane) * Kd;
    int gr = rowBase + (lane & 31); if (gr >= Md) gr = Md - 1;
    const ushort* Ag = j.A + (size_t)gr * Kd + (2 * wid + (lane >> 5)) * 8;

    f32x4 acc[2];
#pragma unroll
    for (int m = 0; m < 2; ++m)
#pragma unroll
        for (int r = 0; r < 4; ++r) acc[m][r] = 0.f;

    auto STAGE = [&](int bf, int tt) {
        const int k0 = tt << 6;
        gll16(Bg + k0 + (2 * wid) * 8,     &Bs[bf][(2 * wid) * 512]);
        gll16(Bg + k0 + (2 * wid + 1) * 8, &Bs[bf][(2 * wid + 1) * 512]);
        gll16(Ag + k0,                     &As[bf][(2 * wid) * 256]);
    };
    auto COMPUTE = [&](int bf) {
#pragma unroll
        for (int kc = 0; kc < 2; ++kc) {
            const int c16 = kc * 4 + (lane >> 4);
            bf16x8 af[2], bfg;
#pragma unroll
            for (int m = 0; m < 2; ++m) {
                const int row = m * 16 + (lane & 15);
                af[m] = *(const bf16x8*)&As[bf][c16 * 256 + row * 8];
            }
            {
                const int rowb = wc * 16 + (lane & 15);
                bfg = *(const bf16x8*)&Bs[bf][c16 * 512 + rowb * 8];
            }
#pragma unroll
            for (int m = 0; m < 2; ++m)
                acc[m] = __builtin_amdgcn_mfma_f32_16x16x32_bf16(af[m], bfg, acc[m], 0, 0, 0);
        }
    };

    const int nt = Kd >> 6;     // 8 or 32 (always >= 2 here)
    STAGE(0, 0);
    STAGE(1, 1);
    asm volatile("s_waitcnt vmcnt(3)" ::: "memory");   // tile 0 resident
    __builtin_amdgcn_s_barrier();
    int bc = 0, bs = 2;
    for (int tt = 0; tt < nt; ++tt) {
        const bool more = (tt + 2) < nt;
        if (more) STAGE(bs, tt + 2);
        COMPUTE(bc);
        if (tt < nt - 1) {
            if (more) asm volatile("s_waitcnt vmcnt(3)" ::: "memory"); // tile tt+1 done
            else      asm volatile("s_waitcnt vmcnt(0)" ::: "memory");
            __builtin_amdgcn_s_barrier();
        }
        bc = bc == 2 ? 0 : bc + 1;
        bs = bs == 2 ? 0 : bs + 1;
    }

    // epilogue: C/D layout col=lane&15, row=(lane>>4)*4+reg  [m89-verified]
    const int cl = lane & 15, rh = lane >> 4;
#pragma unroll
    for (int m = 0; m < 2; ++m) {
        const int col = colBase + wc * 16 + cl;
        const int row0 = rowBase + m * 16 + rh * 4;
#pragma unroll
        for (int r = 0; r < 4; ++r) {
            const int rr = row0 + r;
            if (rr < Md) {
                float v = acc[m][r];
                if (j.flags & 1) v += j.bias[col];
                if (j.flags & 2) v = fmaxf(v, 0.f);
                if (j.resid) v += j.resid[(size_t)rr * Nd + col];
                if (j.Cf) j.Cf[(size_t)rr * Nd + col] = v;
                if (j.Cb) j.Cb[(size_t)rr * Nd + col] = f2bf(v);
            }
        }
    }
}

// ---------------------------------------------------------------------------
// Prep: convert all weights + knowledge + x to bf16 (one pass), copy x -> h.
// ---------------------------------------------------------------------------
struct PrepArgs {
    const float *Wq, *Wk, *Wvs, *Wvo, *Wo, *Wkn, *w1, *w2, *know, *x;
    ushort *wqkvv, *wo, *wkn, *w1b, *w2b, *knowb, *hb;
    float *h;
};
#define P4_WQKVV 1048576
#define P4_B1 (P4_WQKVV + 262144)          // wo
#define P4_B2 (P4_B1 + 262144)             // wkn
#define P4_B3 (P4_B2 + 1048576)            // w1
#define P4_B4 (P4_B3 + 1048576)            // w2
#define P4_B5 (P4_B4 + 128000)             // knowledge
#define P4_TOT (P4_B5 + 65536)             // x

__global__ __launch_bounds__(256) void prep_kernel(PrepArgs p)
{
    const int i = blockIdx.x * 256 + threadIdx.x;
    if (i >= P4_TOT) return;
    const float4* src;
    ushort4* dst;
    if (i < P4_WQKVV) {           // [L][4*512][512]: per-layer concat Wq|Wk|Wvs|Wvo
        const int l = i >> 18, r = i & 262143, q = r >> 16;
        const float* s = (q == 0 ? p.Wq : q == 1 ? p.Wk : q == 2 ? p.Wvs : p.Wvo);
        src = (const float4*)s + l * 65536 + (r & 65535);
        dst = (ushort4*)p.wqkvv + i;
    } else if (i < P4_B1) {
        const int k = i - P4_WQKVV;
        src = (const float4*)p.Wo + k; dst = (ushort4*)p.wo + k;
    } else if (i < P4_B2) {
        const int k = i - P4_B1;
        src = (const float4*)p.Wkn + k; dst = (ushort4*)p.wkn + k;
    } else if (i < P4_B3) {
        const int k = i - P4_B2;
        src = (const float4*)p.w1 + k; dst = (ushort4*)p.w1b + k;
    } else if (i < P4_B4) {
        const int k = i - P4_B3;
        src = (const float4*)p.w2 + k; dst = (ushort4*)p.w2b + k;
    } else if (i < P4_B5) {
        const int k = i - P4_B4;
        src = (const float4*)p.know + k; dst = (ushort4*)p.knowb + k;
    } else {
        const int k = i - P4_B5;
        src = (const float4*)p.x + k; dst = (ushort4*)p.hb + k;
        ((float4*)p.h)[k] = *src;
    }
    float4 v = *src;
    ushort4 o; o.x = f2bf(v.x); o.y = f2bf(v.y); o.z = f2bf(v.z); o.w = f2bf(v.w);
    *dst = o;
}

// ---------------------------------------------------------------------------
// LayerNorm rows of 512 (fp32 in), writes fp32 Yf and bf16 Yb.
// ---------------------------------------------------------------------------
__global__ __launch_bounds__(256) void ln_kernel(
    const float* __restrict__ X, const float* __restrict__ g,
    const float* __restrict__ bt, float* __restrict__ Yf,
    ushort* __restrict__ Yb, int rows)
{
    const int w = threadIdx.x >> 6, lane = threadIdx.x & 63;
    const int row = blockIdx.x * 4 + w;
    if (row >= rows) return;
    const float* x = X + (size_t)row * EE;
    float4 v0 = ((const float4*)x)[lane];
    float4 v1 = ((const float4*)x)[lane + 64];
    float s  = v0.x + v0.y + v0.z + v0.w + v1.x + v1.y + v1.z + v1.w;
    float q2 = v0.x*v0.x + v0.y*v0.y + v0.z*v0.z + v0.w*v0.w
             + v1.x*v1.x + v1.y*v1.y + v1.z*v1.z + v1.w*v1.w;
#pragma unroll
    for (int o = 32; o; o >>= 1) { s += __shfl_xor(s, o); q2 += __shfl_xor(q2, o); }
    const float mean = s * (1.f / EE);
    const float var  = q2 * (1.f / EE) - mean * mean;
    const float rstd = rsqrtf(var + 1e-5f);
    float4 g0 = ((const float4*)g)[lane],  g1 = ((const float4*)g)[lane + 64];
    float4 b0 = ((const float4*)bt)[lane], b1 = ((const float4*)bt)[lane + 64];
    float4 o0, o1;
    o0.x = (v0.x - mean) * rstd * g0.x + b0.x;
    o0.y = (v0.y - mean) * rstd * g0.y + b0.y;
    o0.z = (v0.z - mean) * rstd * g0.z + b0.z;
    o0.w = (v0.w - mean) * rstd * g0.w + b0.w;
    o1.x = (v1.x - mean) * rstd * g1.x + b1.x;
    o1.y = (v1.y - mean) * rstd * g1.y + b1.y;
    o1.z = (v1.z - mean) * rstd * g1.z + b1.z;
    o1.w = (v1.w - mean) * rstd * g1.w + b1.w;
    float* y = Yf + (size_t)row * EE;
    ((float4*)y)[lane] = o0;
    ((float4*)y)[lane + 64] = o1;
    ushort* yb = Yb + (size_t)row * EE;
    ushort4 p0, p1;
    p0.x = f2bf(o0.x); p0.y = f2bf(o0.y); p0.z = f2bf(o0.z); p0.w = f2bf(o0.w);
    p1.x = f2bf(o1.x); p1.y = f2bf(o1.y); p1.z = f2bf(o1.z); p1.w = f2bf(o1.w);
    ((ushort4*)yb)[lane] = p0;
    ((ushort4*)yb)[lane + 64] = p1;
}

// ---------------------------------------------------------------------------
// Fused attention, bf16 activations. qkvv = [512][2048] bf16 (q|k|vs|vo),
// kproj strided LDQ (pre-offset per layer). Output asum bf16 [512][512].
// ---------------------------------------------------------------------------
__global__ __launch_bounds__(256) void attn_kernel(
    const ushort* __restrict__ qkvv, const ushort* __restrict__ kproj,
    const int* __restrict__ know_adj, const int* __restrict__ pos_mask,
    const float* __restrict__ pe_k, const float* __restrict__ pe_v,
    const int* __restrict__ adj, const int* __restrict__ s_mask,
    const int* __restrict__ o_mask, ushort* __restrict__ asum)
{
    const int blk = blockIdx.x;
    const int b = blk >> 7, i = blk & 127;
    const int t = threadIdx.x;

    __shared__ float q_s[EE];
    __shared__ float sc[NH][SS];
    __shared__ float qpe[NH][11];
    __shared__ float ap[NH][11];
    __shared__ float ws_s[SS], wo_s[SS];
    __shared__ int   pos_s[SS], n_s[SS], adj_s[SS];

    // phase 0: q row (bf16 -> f32 LDS) + per-j metadata
    if (t < 64) {
        uint4 v = *(const uint4*)(qkvv + (size_t)(b * SS + i) * LDQ + t * 8);
        float* qd = q_s + t * 8;
        qd[0] = bflo(v.x); qd[1] = bfhi(v.x); qd[2] = bflo(v.y); qd[3] = bfhi(v.y);
        qd[4] = bflo(v.z); qd[5] = bfhi(v.z); qd[6] = bflo(v.w); qd[7] = bfhi(v.w);
    } else if (t >= 128) {
        const int jj = t - 128;
        const size_t off = ((size_t)(b * SS + i)) * SS + jj;
        n_s[jj]   = know_adj[off];
        adj_s[jj] = adj[off];
        ws_s[jj]  = (float)s_mask[off];
        wo_s[jj]  = (float)o_mask[off];
        int p = pos_mask[i * SS + jj];
        pos_s[jj] = p > 10 ? 10 : (p < 0 ? 0 : p);
    }
    __syncthreads();

    // phase 1: qpe[h][p] = q_h . pe_k[p]; zero ap
    if (t < NH * 11) {
        const int h = t / 11, p = t % 11;
        const float* pk = pe_k + p * HD;
        const float* qh = q_s + h * HD;
        float a = 0.f;
#pragma unroll
        for (int d = 0; d < HD; ++d) a += qh[d] * pk[d];
        qpe[h][p] = a;
        ap[h][p] = 0.f;
    }
    __syncthreads();

    // phase 2: scores. thread -> (j = t>>1, half s = t&1 -> 4 heads)
    {
        const int jj = t >> 1, s = t & 1;
        const uint4* kp4 = (const uint4*)(kproj + (size_t)n_s[jj] * LDQ + s * 256);
        const uint4* kr4 = (const uint4*)(qkvv + (size_t)(b * SS + jj) * LDQ + EE + s * 256);
        const float amask = adj_s[jj] ? 0.f : 1e30f;
        const int p = pos_s[jj];
#pragma unroll
        for (int h4 = 0; h4 < 4; ++h4) {
            const int h = s * 4 + h4;
            const float* qh = q_s + h * HD;
            float a = 0.f;
#pragma unroll
            for (int dv = 0; dv < 8; ++dv) {
                uint4 kv = kr4[h4 * 8 + dv];
                uint4 pv = kp4[h4 * 8 + dv];
                const float* q8 = qh + dv * 8;
                a += q8[0] * (bflo(kv.x) + bflo(pv.x));
                a += q8[1] * (bfhi(kv.x) + bfhi(pv.x));
                a += q8[2] * (bflo(kv.y) + bflo(pv.y));
                a += q8[3] * (bfhi(kv.y) + bfhi(pv.y));
                a += q8[4] * (bflo(kv.z) + bflo(pv.z));
                a += q8[5] * (bfhi(kv.z) + bfhi(pv.z));
                a += q8[6] * (bflo(kv.w) + bflo(pv.w));
                a += q8[7] * (bfhi(kv.w) + bfhi(pv.w));
            }
            sc[h][jj] = (a + qpe[h][p]) * 0.125f - amask;
        }
    }
    __syncthreads();

    // phase 3: softmax per head + ap accumulation
    {
        const int w = t >> 6, lane = t & 63;
#pragma unroll
        for (int hh = 0; hh < 2; ++hh) {
            const int h = w * 2 + hh;
            float v0 = sc[h][lane], v1 = sc[h][lane + 64];
            float m = fmaxf(v0, v1);
#pragma unroll
            for (int o = 32; o; o >>= 1) m = fmaxf(m, __shfl_xor(m, o));
            float e0 = __expf(v0 - m), e1 = __expf(v1 - m);
            float ssum = e0 + e1;
#pragma unroll
            for (int o = 32; o; o >>= 1) ssum += __shfl_xor(ssum, o);
            const float inv = 1.f / ssum;
            e0 *= inv; e1 *= inv;
            sc[h][lane] = e0; sc[h][lane + 64] = e1;
            atomicAdd(&ap[h][pos_s[lane]], e0);
            atomicAdd(&ap[h][pos_s[lane + 64]], e1);
        }
    }
    __syncthreads();

    // phase 4: thread t -> head h = t>>5, d pair d0 = (t&31)*2
    {
        const int h = t >> 5, d0 = (t & 31) * 2;
        float a0 = 0.f, a1 = 0.f;
        const ushort* vbase = qkvv + (size_t)b * SS * LDQ + 1024 + h * HD + d0;
#pragma unroll 4
        for (int jj = 0; jj < SS; ++jj) {
            const float aw = sc[h][jj];
            const float wsj = ws_s[jj], woj = wo_s[jj];
            const ushort* r = vbase + (size_t)jj * LDQ;
            const uint vsp = *(const uint*)r;          // vs pair (d0, d0+1)
            const uint vop = *(const uint*)(r + 512);  // vo pair
            a0 += aw * (wsj * bflo(vsp) + woj * bflo(vop));
            a1 += aw * (wsj * bfhi(vsp) + woj * bfhi(vop));
        }
#pragma unroll
        for (int p = 0; p < 11; ++p) {
            const float apv = ap[h][p];
            a0 += apv * pe_v[p * HD + d0];
            a1 += apv * pe_v[p * HD + d0 + 1];
        }
        const uint o = (uint)f2bf(a0) | ((uint)f2bf(a1) << 16);
        *(uint*)(asum + (size_t)(b * SS + i) * EE + h * HD + d0) = o;
    }
}

// ---------------------------------------------------------------------------
extern "C" void kernel_launch(void* const* d_in, const int* in_sizes, int n_in,
                              void* d_out, int out_size, void* d_ws, size_t ws_size,
                              hipStream_t stream)
{
    const float* x         = (const float*)d_in[0];
    const int*   adj       = (const int*)d_in[1];
    const int*   s_mask    = (const int*)d_in[2];
    const int*   o_mask    = (const int*)d_in[3];
    const float* knowledge = (const float*)d_in[4];
    const int*   know_adj  = (const int*)d_in[5];
    const int*   pos_mask  = (const int*)d_in[6];
    const float* pe_k      = (const float*)d_in[7];
    const float* pe_v      = (const float*)d_in[8];
    const float* Wq        = (const float*)d_in[9];
    const float* Wk        = (const float*)d_in[10];
    const float* Wvs       = (const float*)d_in[11];
    const float* Wvo       = (const float*)d_in[12];
    const float* Wo        = (const float*)d_in[13];
    const float* Wkn       = (const float*)d_in[14];
    const float* ln1_g     = (const float*)d_in[15];
    const float* ln1_b     = (const float*)d_in[16];
    const float* w1        = (const float*)d_in[17];
    const float* b1        = (const float*)d_in[18];
    const float* w2        = (const float*)d_in[19];
    const float* b2        = (const float*)d_in[20];
    const float* ln2_g     = (const float*)d_in[21];
    const float* ln2_b     = (const float*)d_in[22];

    const int NTOK = BB * SS;                 // 512
    const size_t NTE = (size_t)NTOK * EE;     // 262144

    // workspace layout
    float*  h      = (float*)d_ws;            // 1 MB
    float*  xt     = h + NTE;                 // 1 MB
    ushort* hb     = (ushort*)(xt + NTE);     // 512 KB
    ushort* qkvv   = hb + NTE;                // 2 MB
    ushort* kprojb = qkvv + (size_t)NTOK * LDQ;        // [1000(pad 1024)][2048] 4 MB
    ushort* asumb  = kprojb + (size_t)1024 * LDQ;      // 512 KB
    ushort* ffnb   = asumb + NTE;             // 2 MB
    ushort* wqkvv  = ffnb + (size_t)NTOK * FFD;        // 8 MB
    ushort* wob    = wqkvv + (size_t)NL * 4 * EE * EE; // 2 MB
    ushort* wknb   = wob + (size_t)NL * EE * EE;       // 2 MB
    ushort* w1b    = wknb + (size_t)NL * EE * EE;      // 8 MB
    ushort* w2b    = w1b + (size_t)NL * FFD * EE;      // 8 MB
    ushort* knowb  = w2b + (size_t)NL * EE * FFD;      // 1 MB

    PrepArgs pa;
    pa.Wq = Wq; pa.Wk = Wk; pa.Wvs = Wvs; pa.Wvo = Wvo; pa.Wo = Wo; pa.Wkn = Wkn;
    pa.w1 = w1; pa.w2 = w2; pa.know = knowledge; pa.x = x;
    pa.wqkvv = wqkvv; pa.wo = wob; pa.wkn = wknb; pa.w1b = w1b; pa.w2b = w2b;
    pa.knowb = knowb; pa.hb = hb; pa.h = h;
    prep_kernel<<<dim3((P4_TOT + 255) / 256), dim3(256), 0, stream>>>(pa);

    const dim3 blk(256);
    for (int l = 0; l < NL; ++l) {
        GemmJob jq{};   // QKVV concat: [512,2048] = h @ Wqkvv_l^T   (512 blocks)
        jq.A = hb; jq.B = wqkvv + (size_t)l * 4 * EE * EE;
        jq.Cb = qkvv; jq.M = NTOK; jq.N = 4 * EE; jq.K = EE;
        jq.nbx = 32; jq.base = 0;
        if (l == 0) {
            // batch layer-0 QKVV with ALL layers' kproj:
            // kproj_all [1000,2048] = knowledge @ Wkn_stacked^T (cols l*512..)
            GemmJob jk{};
            jk.A = knowb; jk.B = wknb;
            jk.Cb = kprojb; jk.M = 1000; jk.N = NL * EE; jk.K = EE;
            jk.nbx = 32; jk.base = 512;
            gemm_bf16<<<dim3(512 + 1024), blk, 0, stream>>>(jq, jk, 2);
        } else {
            gemm_bf16<<<dim3(512), blk, 0, stream>>>(jq, jq, 1);
        }

        attn_kernel<<<dim3(NTOK), blk, 0, stream>>>(qkvv, kprojb + (size_t)l * EE,
                                                    know_adj, pos_mask,
                                                    pe_k, pe_v, adj, s_mask, o_mask, asumb);

        GemmJob jo{};   // Wo: xt = asum @ Wo_l^T + h   (128 blocks)
        jo.A = asumb; jo.B = wob + (size_t)l * EE * EE;
        jo.Cf = xt; jo.resid = h; jo.M = NTOK; jo.N = EE; jo.K = EE;
        jo.nbx = 8; jo.base = 0;
        gemm_bf16<<<dim3(128), blk, 0, stream>>>(jo, jo, 1);

        ln_kernel<<<dim3(128), blk, 0, stream>>>(xt, ln1_g + l * EE, ln1_b + l * EE,
                                                 h, hb, NTOK);

        GemmJob jf1{};  // FFN1: relu(h @ w1_l^T + b1) -> bf16   (512 blocks)
        jf1.A = hb; jf1.B = w1b + (size_t)l * FFD * EE;
        jf1.Cb = ffnb; jf1.bias = b1 + (size_t)l * FFD; jf1.flags = 3;
        jf1.M = NTOK; jf1.N = FFD; jf1.K = EE; jf1.nbx = 32; jf1.base = 0;
        gemm_bf16<<<dim3(512), blk, 0, stream>>>(jf1, jf1, 1);

        GemmJob jf2{};  // FFN2: xt = ffn @ w2_l^T + b2 + h   (128 blocks, 32 K-steps)
        jf2.A = ffnb; jf2.B = w2b + (size_t)l * EE * FFD;
        jf2.Cf = xt; jf2.bias = b2 + (size_t)l * EE; jf2.resid = h; jf2.flags = 1;
        jf2.M = NTOK; jf2.N = EE; jf2.K = FFD; jf2.nbx = 8; jf2.base = 0;
        gemm_bf16<<<dim3(128), blk, 0, stream>>>(jf2, jf2, 1);

        float* lnout = (l == NL - 1) ? (float*)d_out : h;
        ln_kernel<<<dim3(128), blk, 0, stream>>>(xt, ln2_g + l * EE, ln2_b + l * EE,
                                                 lnout, hb, NTOK);
    }
}

// Round 6
// 525.889 us; speedup vs baseline: 1.0994x; 1.0994x over previous
//
#include <hip/hip_runtime.h>

#define EE 512
#define SS 128
#define BB 4
#define NH 8
#define HD 64
#define FFD 2048
#define NL 4
#define LDQ 2048   // qkvv concat leading dim; also kproj_ext row stride

typedef short bf16x8 __attribute__((ext_vector_type(8)));
typedef float f32x4 __attribute__((ext_vector_type(4)));

__device__ __forceinline__ ushort f2bf(float f) {
    uint u = __float_as_uint(f);
    return (ushort)((u + 0x7fffu + ((u >> 16) & 1u)) >> 16);
}
__device__ __forceinline__ float bflo(uint u) { return __uint_as_float(u << 16); }
__device__ __forceinline__ float bfhi(uint u) { return __uint_as_float(u & 0xffff0000u); }

// async 16B global->LDS. LDS dest = wave-uniform base + lane*16 (HW rule).
__device__ __forceinline__ void gll16(const ushort* g, ushort* l) {
    __builtin_amdgcn_global_load_lds(
        (const __attribute__((address_space(1))) void*)g,
        (__attribute__((address_space(3))) void*)l, 16, 0, 0);
}

// ---------------------------------------------------------------------------
// bf16 MFMA GEMM, 3-buffer depth-2 global_load_lds pipeline, counted vmcnt.
// C[M,N] = A[M,K] @ B[N,K]^T.  BM=32, BN=64, BK=64, 256 thr / 4 waves.
// (unchanged from round 5 — passed)
// ---------------------------------------------------------------------------
struct GemmJob {
    const ushort* A; const ushort* B;
    float* Cf; ushort* Cb;
    const float* bias; const float* resid;
    int M, N, K, flags, nbx, base;
};

__global__ __launch_bounds__(256) void gemm_bf16(GemmJob j0, GemmJob j1, int njobs)
{
    __shared__ ushort As[3][2048];   // 3 x 4KB  (8 chunks x 32 rows x 16B)
    __shared__ ushort Bs[3][4096];   // 3 x 8KB  (8 chunks x 64 rows x 16B)
    GemmJob j = (njobs > 1 && (int)blockIdx.x >= j1.base) ? j1 : j0;
    const int bid = (int)blockIdx.x - j.base;
    const int by = bid / j.nbx, bx = bid % j.nbx;
    const int rowBase = by * 32, colBase = bx * 64;
    const int t = threadIdx.x, lane = t & 63, wid = t >> 6;
    const int wc = wid;
    const int Kd = j.K, Md = j.M, Nd = j.N;

    const ushort* Bg = j.B + (size_t)(colBase + lane) * Kd;
    int gr = rowBase + (lane & 31); if (gr >= Md) gr = Md - 1;
    const ushort* Ag = j.A + (size_t)gr * Kd + (2 * wid + (lane >> 5)) * 8;

    f32x4 acc[2];
#pragma unroll
    for (int m = 0; m < 2; ++m)
#pragma unroll
        for (int r = 0; r < 4; ++r) acc[m][r] = 0.f;

    auto STAGE = [&](int bf, int tt) {
        const int k0 = tt << 6;
        gll16(Bg + k0 + (2 * wid) * 8,     &Bs[bf][(2 * wid) * 512]);
        gll16(Bg + k0 + (2 * wid + 1) * 8, &Bs[bf][(2 * wid + 1) * 512]);
        gll16(Ag + k0,                     &As[bf][(2 * wid) * 256]);
    };
    auto COMPUTE = [&](int bf) {
#pragma unroll
        for (int kc = 0; kc < 2; ++kc) {
            const int c16 = kc * 4 + (lane >> 4);
            bf16x8 af[2], bfg;
#pragma unroll
            for (int m = 0; m < 2; ++m) {
                const int row = m * 16 + (lane & 15);
                af[m] = *(const bf16x8*)&As[bf][c16 * 256 + row * 8];
            }
            {
                const int rowb = wc * 16 + (lane & 15);
                bfg = *(const bf16x8*)&Bs[bf][c16 * 512 + rowb * 8];
            }
#pragma unroll
            for (int m = 0; m < 2; ++m)
                acc[m] = __builtin_amdgcn_mfma_f32_16x16x32_bf16(af[m], bfg, acc[m], 0, 0, 0);
        }
    };

    const int nt = Kd >> 6;
    STAGE(0, 0);
    STAGE(1, 1);
    asm volatile("s_waitcnt vmcnt(3)" ::: "memory");
    __builtin_amdgcn_s_barrier();
    int bc = 0, bs = 2;
    for (int tt = 0; tt < nt; ++tt) {
        const bool more = (tt + 2) < nt;
        if (more) STAGE(bs, tt + 2);
        COMPUTE(bc);
        if (tt < nt - 1) {
            if (more) asm volatile("s_waitcnt vmcnt(3)" ::: "memory");
            else      asm volatile("s_waitcnt vmcnt(0)" ::: "memory");
            __builtin_amdgcn_s_barrier();
        }
        bc = bc == 2 ? 0 : bc + 1;
        bs = bs == 2 ? 0 : bs + 1;
    }

    const int cl = lane & 15, rh = lane >> 4;
#pragma unroll
    for (int m = 0; m < 2; ++m) {
        const int col = colBase + wc * 16 + cl;
        const int row0 = rowBase + m * 16 + rh * 4;
#pragma unroll
        for (int r = 0; r < 4; ++r) {
            const int rr = row0 + r;
            if (rr < Md) {
                float v = acc[m][r];
                if (j.flags & 1) v += j.bias[col];
                if (j.flags & 2) v = fmaxf(v, 0.f);
                if (j.resid) v += j.resid[(size_t)rr * Nd + col];
                if (j.Cf) j.Cf[(size_t)rr * Nd + col] = v;
                if (j.Cb) j.Cb[(size_t)rr * Nd + col] = f2bf(v);
            }
        }
    }
}

// ---------------------------------------------------------------------------
// score_gemm: per-layer MFMA scores. K=64 single-step, strided A/B (lda=2048).
//   blocks 0..255   : qk[b,i,h,j]  = Q_h K_h^T   per (b,h)  [f32, [b][i][h][j]]
//   blocks 256..2303: qkk[bi,h,n]  = Q_h kproj_ext_h^T      [f32, [bi][h][1024]]
//     kproj_ext rows 0..999 = knowledge@Wkn_l; rows 1000..1010 = pe_k
//     so qkk[...][1000+p] = q_h . pe_k[p]  (the qpe table, free).
// ---------------------------------------------------------------------------
__global__ __launch_bounds__(256) void score_gemm(
    const ushort* __restrict__ qkvv, const ushort* __restrict__ kprojl,
    float* __restrict__ qk, float* __restrict__ qkk)
{
    __shared__ ushort As[2048];
    __shared__ ushort Bs[4096];
    const int t = threadIdx.x, lane = t & 63, wid = t >> 6;
    const int bid = blockIdx.x;
    const ushort *Abase, *Bbase;
    float* Cbase; int crs, rowBase, colBase;
    if (bid < 256) {
        const int q = bid >> 3, sub = bid & 7;
        const int b = q >> 3, h = q & 7;
        rowBase = (sub >> 1) * 32; colBase = (sub & 1) * 64;
        Abase = qkvv + (size_t)(b * SS) * LDQ + h * HD;
        Bbase = qkvv + (size_t)(b * SS) * LDQ + 512 + h * HD;
        Cbase = qk + (size_t)b * 131072 + h * 128;
        crs = 1024;
    } else {
        const int idx = bid - 256;
        const int h = idx >> 8, sub = idx & 255;
        rowBase = (sub >> 4) * 32; colBase = (sub & 15) * 64;
        Abase = qkvv + h * HD;
        Bbase = kprojl + h * HD;
        Cbase = qkk + (size_t)h * 1024;
        crs = 8192;
    }
    // stage full K=64 (one tile)
    {
        const ushort* Bg = Bbase + (size_t)(colBase + lane) * LDQ;
        const ushort* Ag = Abase + (size_t)(rowBase + (lane & 31)) * LDQ
                           + (2 * wid + (lane >> 5)) * 8;
        gll16(Bg + (2 * wid) * 8,     &Bs[(2 * wid) * 512]);
        gll16(Bg + (2 * wid + 1) * 8, &Bs[(2 * wid + 1) * 512]);
        gll16(Ag,                     &As[(2 * wid) * 256]);
        asm volatile("s_waitcnt vmcnt(0)" ::: "memory");
        __builtin_amdgcn_s_barrier();
    }
    f32x4 acc[2];
#pragma unroll
    for (int m = 0; m < 2; ++m)
#pragma unroll
        for (int r = 0; r < 4; ++r) acc[m][r] = 0.f;
#pragma unroll
    for (int kc = 0; kc < 2; ++kc) {
        const int c16 = kc * 4 + (lane >> 4);
        bf16x8 af[2], bfg;
#pragma unroll
        for (int m = 0; m < 2; ++m) {
            const int row = m * 16 + (lane & 15);
            af[m] = *(const bf16x8*)&As[c16 * 256 + row * 8];
        }
        {
            const int rowb = wid * 16 + (lane & 15);
            bfg = *(const bf16x8*)&Bs[c16 * 512 + rowb * 8];
        }
#pragma unroll
        for (int m = 0; m < 2; ++m)
            acc[m] = __builtin_amdgcn_mfma_f32_16x16x32_bf16(af[m], bfg, acc[m], 0, 0, 0);
    }
    const int cl = lane & 15, rh = lane >> 4;
#pragma unroll
    for (int m = 0; m < 2; ++m) {
        const int col = colBase + wid * 16 + cl;
        const int row0 = rowBase + m * 16 + rh * 4;
#pragma unroll
        for (int r = 0; r < 4; ++r)
            Cbase[(size_t)(row0 + r) * crs + col] = acc[m][r];
    }
}

// ---------------------------------------------------------------------------
// Prep: weights/knowledge/x -> bf16; replicate pe_k into kproj_ext rows
// 1000..1010 (cols repeated per layer,head).
// ---------------------------------------------------------------------------
struct PrepArgs {
    const float *Wq, *Wk, *Wvs, *Wvo, *Wo, *Wkn, *w1, *w2, *know, *x, *pek;
    ushort *wqkvv, *wo, *wkn, *w1b, *w2b, *knowb, *hb, *kpe;
    float *h;
};
#define P4_WQKVV 1048576
#define P4_B1 (P4_WQKVV + 262144)          // wo
#define P4_B2 (P4_B1 + 262144)             // wkn
#define P4_B3 (P4_B2 + 1048576)            // w1
#define P4_B4 (P4_B3 + 1048576)            // w2
#define P4_B5 (P4_B4 + 128000)             // knowledge
#define P4_B6 (P4_B5 + 65536)              // x
#define P4_TOT (P4_B6 + 5632)              // pe_k -> kproj_ext rows

__global__ __launch_bounds__(256) void prep_kernel(PrepArgs pa)
{
    const int i = blockIdx.x * 256 + threadIdx.x;
    if (i >= P4_TOT) return;
    const float4* src;
    ushort4* dst;
    if (i < P4_WQKVV) {           // [L][4*512][512]: per-layer concat Wq|Wk|Wvs|Wvo
        const int l = i >> 18, r = i & 262143, q = r >> 16;
        const float* s = (q == 0 ? pa.Wq : q == 1 ? pa.Wk : q == 2 ? pa.Wvs : pa.Wvo);
        src = (const float4*)s + l * 65536 + (r & 65535);
        dst = (ushort4*)pa.wqkvv + i;
    } else if (i < P4_B1) {
        const int k = i - P4_WQKVV;
        src = (const float4*)pa.Wo + k; dst = (ushort4*)pa.wo + k;
    } else if (i < P4_B2) {
        const int k = i - P4_B1;
        src = (const float4*)pa.Wkn + k; dst = (ushort4*)pa.wkn + k;
    } else if (i < P4_B3) {
        const int k = i - P4_B2;
        src = (const float4*)pa.w1 + k; dst = (ushort4*)pa.w1b + k;
    } else if (i < P4_B4) {
        const int k = i - P4_B3;
        src = (const float4*)pa.w2 + k; dst = (ushort4*)pa.w2b + k;
    } else if (i < P4_B5) {
        const int k = i - P4_B4;
        src = (const float4*)pa.know + k; dst = (ushort4*)pa.knowb + k;
    } else if (i < P4_B6) {
        const int k = i - P4_B5;
        src = (const float4*)pa.x + k; dst = (ushort4*)pa.hb + k;
        ((float4*)pa.h)[k] = *src;
    } else {                       // pe_k replicate: row 1000+p, col c in [0,2048)
        const int k = i - P4_B6;   // 0..5631
        const int c4 = k * 4;
        const int p = c4 >> 11, col = c4 & 2047, d = col & 63;
        src = (const float4*)(pa.pek + p * 64 + d);
        dst = (ushort4*)(pa.kpe + (size_t)(1000 + p) * 2048 + col);
    }
    float4 v = *src;
    ushort4 o; o.x = f2bf(v.x); o.y = f2bf(v.y); o.z = f2bf(v.z); o.w = f2bf(v.w);
    *dst = o;
}

// ---------------------------------------------------------------------------
// LayerNorm rows of 512 (fp32 in), writes fp32 Yf and bf16 Yb.
// ---------------------------------------------------------------------------
__global__ __launch_bounds__(256) void ln_kernel(
    const float* __restrict__ X, const float* __restrict__ g,
    const float* __restrict__ bt, float* __restrict__ Yf,
    ushort* __restrict__ Yb, int rows)
{
    const int w = threadIdx.x >> 6, lane = threadIdx.x & 63;
    const int row = blockIdx.x * 4 + w;
    if (row >= rows) return;
    const float* x = X + (size_t)row * EE;
    float4 v0 = ((const float4*)x)[lane];
    float4 v1 = ((const float4*)x)[lane + 64];
    float s  = v0.x + v0.y + v0.z + v0.w + v1.x + v1.y + v1.z + v1.w;
    float q2 = v0.x*v0.x + v0.y*v0.y + v0.z*v0.z + v0.w*v0.w
             + v1.x*v1.x + v1.y*v1.y + v1.z*v1.z + v1.w*v1.w;
#pragma unroll
    for (int o = 32; o; o >>= 1) { s += __shfl_xor(s, o); q2 += __shfl_xor(q2, o); }
    const float mean = s * (1.f / EE);
    const float var  = q2 * (1.f / EE) - mean * mean;
    const float rstd = rsqrtf(var + 1e-5f);
    float4 g0 = ((const float4*)g)[lane],  g1 = ((const float4*)g)[lane + 64];
    float4 b0 = ((const float4*)bt)[lane], b1 = ((const float4*)bt)[lane + 64];
    float4 o0, o1;
    o0.x = (v0.x - mean) * rstd * g0.x + b0.x;
    o0.y = (v0.y - mean) * rstd * g0.y + b0.y;
    o0.z = (v0.z - mean) * rstd * g0.z + b0.z;
    o0.w = (v0.w - mean) * rstd * g0.w + b0.w;
    o1.x = (v1.x - mean) * rstd * g1.x + b1.x;
    o1.y = (v1.y - mean) * rstd * g1.y + b1.y;
    o1.z = (v1.z - mean) * rstd * g1.z + b1.z;
    o1.w = (v1.w - mean) * rstd * g1.w + b1.w;
    float* y = Yf + (size_t)row * EE;
    ((float4*)y)[lane] = o0;
    ((float4*)y)[lane + 64] = o1;
    ushort* yb = Yb + (size_t)row * EE;
    ushort4 p0, p1;
    p0.x = f2bf(o0.x); p0.y = f2bf(o0.y); p0.z = f2bf(o0.z); p0.w = f2bf(o0.w);
    p1.x = f2bf(o1.x); p1.y = f2bf(o1.y); p1.z = f2bf(o1.z); p1.w = f2bf(o1.w);
    ((ushort4*)yb)[lane] = p0;
    ((ushort4*)yb)[lane + 64] = p1;
}

// ---------------------------------------------------------------------------
// Attention (gather + softmax + AV). Scores precomputed via score_gemm:
//   sc[h][j] = (qk[b,i,h,j] + qkk[bi,h,n_j] + qkk[bi,h,1000+pos_j])*0.125 - mask
// ---------------------------------------------------------------------------
__global__ __launch_bounds__(256) void attn_kernel(
    const ushort* __restrict__ qkvv, const float* __restrict__ qk,
    const float* __restrict__ qkk,
    const int* __restrict__ know_adj, const int* __restrict__ pos_mask,
    const float* __restrict__ pe_v,
    const int* __restrict__ adj, const int* __restrict__ s_mask,
    const int* __restrict__ o_mask, ushort* __restrict__ asum)
{
    const int blk = blockIdx.x;
    const int b = blk >> 7, i = blk & 127;
    const int t = threadIdx.x;

    __shared__ float sc[NH][SS];
    __shared__ float ap[NH][11];
    __shared__ float ws_s[SS], wo_s[SS], amask_s[SS];
    __shared__ int   pos_s[SS], n_s[SS];

    const float* qkrow  = qk + (size_t)b * 131072 + (size_t)i * 1024;
    const float* qkkrow = qkk + (size_t)(b * SS + i) * 8192;

    // P0: metadata (t<128) + qk row -> sc (t>=128, flat copy)
    if (t < 128) {
        const int jj = t;
        const size_t off = ((size_t)(b * SS + i)) * SS + jj;
        n_s[jj]     = know_adj[off];
        amask_s[jj] = adj[off] ? 0.f : 1e30f;
        ws_s[jj]    = (float)s_mask[off];
        wo_s[jj]    = (float)o_mask[off];
        int p = pos_mask[i * SS + jj];
        pos_s[jj] = p > 10 ? 10 : (p < 0 ? 0 : p);
        if (t < 88) ap[t / 11][t % 11] = 0.f;
    } else {
        const int tt = t - 128;
        ((float4*)&sc[0][0])[tt]       = ((const float4*)qkrow)[tt];
        ((float4*)&sc[0][0])[tt + 128] = ((const float4*)qkrow)[tt + 128];
    }
    __syncthreads();

    // P1: score assembly. t -> h = t>>5, j = (t&31)*4 .. +3
    {
        const int h = t >> 5, j0 = (t & 31) * 4;
        const float* qh = qkkrow + h * 1024;
#pragma unroll
        for (int u = 0; u < 4; ++u) {
            const int jj = j0 + u;
            const float v = sc[h][jj] + qh[n_s[jj]] + qh[1000 + pos_s[jj]];
            sc[h][jj] = v * 0.125f - amask_s[jj];
        }
    }
    __syncthreads();

    // P2: softmax per head + ap accumulation
    {
        const int w = t >> 6, lane = t & 63;
#pragma unroll
        for (int hh = 0; hh < 2; ++hh) {
            const int h = w * 2 + hh;
            float v0 = sc[h][lane], v1 = sc[h][lane + 64];
            float m = fmaxf(v0, v1);
#pragma unroll
            for (int o = 32; o; o >>= 1) m = fmaxf(m, __shfl_xor(m, o));
            float e0 = __expf(v0 - m), e1 = __expf(v1 - m);
            float ssum = e0 + e1;
#pragma unroll
            for (int o = 32; o; o >>= 1) ssum += __shfl_xor(ssum, o);
            const float inv = 1.f / ssum;
            e0 *= inv; e1 *= inv;
            sc[h][lane] = e0; sc[h][lane + 64] = e1;
            atomicAdd(&ap[h][pos_s[lane]], e0);
            atomicAdd(&ap[h][pos_s[lane + 64]], e1);
        }
    }
    __syncthreads();

    // P3: output. t -> h = t>>5, d pair d0 = (t&31)*2; 8-j load batches for MLP.
    {
        const int h = t >> 5, d0 = (t & 31) * 2;
        float a0 = 0.f, a1 = 0.f;
        const ushort* vbase = qkvv + (size_t)b * SS * LDQ + 1024 + h * HD + d0;
        for (int j0 = 0; j0 < SS; j0 += 8) {
            uint vsp[8], vop[8];
#pragma unroll
            for (int u = 0; u < 8; ++u) {
                const ushort* r = vbase + (size_t)(j0 + u) * LDQ;
                vsp[u] = *(const uint*)r;
                vop[u] = *(const uint*)(r + 512);
            }
#pragma unroll
            for (int u = 0; u < 8; ++u) {
                const int jj = j0 + u;
                const float aw = sc[h][jj];
                const float wsj = ws_s[jj], woj = wo_s[jj];
                a0 += aw * (wsj * bflo(vsp[u]) + woj * bflo(vop[u]));
                a1 += aw * (wsj * bfhi(vsp[u]) + woj * bfhi(vop[u]));
            }
        }
#pragma unroll
        for (int p = 0; p < 11; ++p) {
            const float apv = ap[h][p];
            a0 += apv * pe_v[p * HD + d0];
            a1 += apv * pe_v[p * HD + d0 + 1];
        }
        const uint o = (uint)f2bf(a0) | ((uint)f2bf(a1) << 16);
        *(uint*)(asum + (size_t)(b * SS + i) * EE + h * HD + d0) = o;
    }
}

// ---------------------------------------------------------------------------
extern "C" void kernel_launch(void* const* d_in, const int* in_sizes, int n_in,
                              void* d_out, int out_size, void* d_ws, size_t ws_size,
                              hipStream_t stream)
{
    const float* x         = (const float*)d_in[0];
    const int*   adj       = (const int*)d_in[1];
    const int*   s_mask    = (const int*)d_in[2];
    const int*   o_mask    = (const int*)d_in[3];
    const float* knowledge = (const float*)d_in[4];
    const int*   know_adj  = (const int*)d_in[5];
    const int*   pos_mask  = (const int*)d_in[6];
    const float* pe_k      = (const float*)d_in[7];
    const float* pe_v      = (const float*)d_in[8];
    const float* Wq        = (const float*)d_in[9];
    const float* Wk        = (const float*)d_in[10];
    const float* Wvs       = (const float*)d_in[11];
    const float* Wvo       = (const float*)d_in[12];
    const float* Wo        = (const float*)d_in[13];
    const float* Wkn       = (const float*)d_in[14];
    const float* ln1_g     = (const float*)d_in[15];
    const float* ln1_b     = (const float*)d_in[16];
    const float* w1        = (const float*)d_in[17];
    const float* b1        = (const float*)d_in[18];
    const float* w2        = (const float*)d_in[19];
    const float* b2        = (const float*)d_in[20];
    const float* ln2_g     = (const float*)d_in[21];
    const float* ln2_b     = (const float*)d_in[22];

    const int NTOK = BB * SS;                 // 512
    const size_t NTE = (size_t)NTOK * EE;     // 262144

    // workspace layout
    float*  h      = (float*)d_ws;                     // 1 MB
    float*  xt     = h + NTE;                          // 1 MB
    float*  qk     = xt + NTE;                         // [b][i][h][j] 2 MB
    float*  qkk    = qk + (size_t)NTOK * 1024;         // [bi][h][1024] 16 MB
    ushort* hb     = (ushort*)(qkk + (size_t)NTOK * 8192);  // 512 KB
    ushort* qkvv   = hb + NTE;                         // 2 MB
    ushort* kprojb = qkvv + (size_t)NTOK * LDQ;        // [1024][2048] 4 MB
    ushort* asumb  = kprojb + (size_t)1024 * LDQ;      // 512 KB
    ushort* ffnb   = asumb + NTE;                      // 2 MB
    ushort* wqkvv  = ffnb + (size_t)NTOK * FFD;        // 8 MB
    ushort* wob    = wqkvv + (size_t)NL * 4 * EE * EE; // 2 MB
    ushort* wknb   = wob + (size_t)NL * EE * EE;       // 2 MB
    ushort* w1b    = wknb + (size_t)NL * EE * EE;      // 8 MB
    ushort* w2b    = w1b + (size_t)NL * FFD * EE;      // 8 MB
    ushort* knowb  = w2b + (size_t)NL * EE * FFD;      // 1 MB

    PrepArgs pa;
    pa.Wq = Wq; pa.Wk = Wk; pa.Wvs = Wvs; pa.Wvo = Wvo; pa.Wo = Wo; pa.Wkn = Wkn;
    pa.w1 = w1; pa.w2 = w2; pa.know = knowledge; pa.x = x; pa.pek = pe_k;
    pa.wqkvv = wqkvv; pa.wo = wob; pa.wkn = wknb; pa.w1b = w1b; pa.w2b = w2b;
    pa.knowb = knowb; pa.hb = hb; pa.h = h; pa.kpe = kprojb;
    prep_kernel<<<dim3((P4_TOT + 255) / 256), dim3(256), 0, stream>>>(pa);

    const dim3 blk(256);
    for (int l = 0; l < NL; ++l) {
        GemmJob jq{};   // QKVV concat: [512,2048] = h @ Wqkvv_l^T   (512 blocks)
        jq.A = hb; jq.B = wqkvv + (size_t)l * 4 * EE * EE;
        jq.Cb = qkvv; jq.M = NTOK; jq.N = 4 * EE; jq.K = EE;
        jq.nbx = 32; jq.base = 0;
        if (l == 0) {
            // batch layer-0 QKVV with ALL layers' kproj (rows 0..999; M=1000
            // row-guard protects the pe_k rows 1000..1010 written by prep)
            GemmJob jk{};
            jk.A = knowb; jk.B = wknb;
            jk.Cb = kprojb; jk.M = 1000; jk.N = NL * EE; jk.K = EE;
            jk.nbx = 32; jk.base = 512;
            gemm_bf16<<<dim3(512 + 1024), blk, 0, stream>>>(jq, jk, 2);
        } else {
            gemm_bf16<<<dim3(512), blk, 0, stream>>>(jq, jq, 1);
        }

        score_gemm<<<dim3(2304), blk, 0, stream>>>(qkvv, kprojb + (size_t)l * EE,
                                                   qk, qkk);

        attn_kernel<<<dim3(NTOK), blk, 0, stream>>>(qkvv, qk, qkk,
                                                    know_adj, pos_mask, pe_v,
                                                    adj, s_mask, o_mask, asumb);

        GemmJob jo{};   // Wo: xt = asum @ Wo_l^T + h   (128 blocks)
        jo.A = asumb; jo.B = wob + (size_t)l * EE * EE;
        jo.Cf = xt; jo.resid = h; jo.M = NTOK; jo.N = EE; jo.K = EE;
        jo.nbx = 8; jo.base = 0;
        gemm_bf16<<<dim3(128), blk, 0, stream>>>(jo, jo, 1);

        ln_kernel<<<dim3(128), blk, 0, stream>>>(xt, ln1_g + l * EE, ln1_b + l * EE,
                                                 h, hb, NTOK);

        GemmJob jf1{};  // FFN1: relu(h @ w1_l^T + b1) -> bf16   (512 blocks)
        jf1.A = hb; jf1.B = w1b + (size_t)l * FFD * EE;
        jf1.Cb = ffnb; jf1.bias = b1 + (size_t)l * FFD; jf1.flags = 3;
        jf1.M = NTOK; jf1.N = FFD; jf1.K = EE; jf1.nbx = 32; jf1.base = 0;
        gemm_bf16<<<dim3(512), blk, 0, stream>>>(jf1, jf1, 1);

        GemmJob jf2{};  // FFN2: xt = ffn @ w2_l^T + b2 + h   (128 blocks)
        jf2.A = ffnb; jf2.B = w2b + (size_t)l * EE * FFD;
        jf2.Cf = xt; jf2.bias = b2 + (size_t)l * EE; jf2.resid = h; jf2.flags = 1;
        jf2.M = NTOK; jf2.N = EE; jf2.K = FFD; jf2.nbx = 8; jf2.base = 0;
        gemm_bf16<<<dim3(128), blk, 0, stream>>>(jf2, jf2, 1);

        float* lnout = (l == NL - 1) ? (float*)d_out : h;
        ln_kernel<<<dim3(128), blk, 0, stream>>>(xt, ln2_g + l * EE, ln2_b + l * EE,
                                                 lnout, hb, NTOK);
    }
}

// Round 7
// 503.771 us; speedup vs baseline: 1.1477x; 1.0439x over previous
//
#include <hip/hip_runtime.h>

#define EE 512
#define SS 128
#define BB 4
#define NH 8
#define HD 64
#define FFD 2048
#define NL 4
#define LDQ 2048   // qkvv concat leading dim; also kproj_ext row stride
#define KEXT 320   // PV extended K: 128 vs + 128 vo + 11 ap + pad
#define PSTR 136   // Ps LDS chunk stride (ushorts)

typedef short bf16x8 __attribute__((ext_vector_type(8)));
typedef float f32x4 __attribute__((ext_vector_type(4)));

__device__ __forceinline__ ushort f2bf(float f) {
    uint u = __float_as_uint(f);
    return (ushort)((u + 0x7fffu + ((u >> 16) & 1u)) >> 16);
}
__device__ __forceinline__ float bflo(uint u) { return __uint_as_float(u << 16); }
__device__ __forceinline__ float bfhi(uint u) { return __uint_as_float(u & 0xffff0000u); }

// async 16B global->LDS. LDS dest = wave-uniform base + lane*16 (HW rule);
// global source address is per-lane.
__device__ __forceinline__ void gll16(const ushort* g, ushort* l) {
    __builtin_amdgcn_global_load_lds(
        (const __attribute__((address_space(1))) void*)g,
        (__attribute__((address_space(3))) void*)l, 16, 0, 0);
}

// ---------------------------------------------------------------------------
// bf16 MFMA GEMM, 4-buffer depth-3 global_load_lds pipeline, counted vmcnt.
// C[M,N] = A[M,K] @ B[N,K]^T.  BM=32, BN=64, BK=64, 256 thr / 4 waves.
// flags: bit0=+bias[col], bit1=relu, bit2=V-transpose write for cols>=1024.
// ---------------------------------------------------------------------------
struct GemmJob {
    const ushort* A; const ushort* B;
    float* Cf; ushort* Cb; ushort* vext;
    const float* bias; const float* resid;
    int M, N, K, flags, nbx, base;
};

__global__ __launch_bounds__(256) void gemm_bf16(GemmJob j0, GemmJob j1, int njobs)
{
    __shared__ ushort As[4][2048];   // 4 x 4KB  (8 chunks x 32 rows x 16B)
    __shared__ ushort Bs[4][4096];   // 4 x 8KB  (8 chunks x 64 rows x 16B)
    GemmJob j = (njobs > 1 && (int)blockIdx.x >= j1.base) ? j1 : j0;
    const int bid = (int)blockIdx.x - j.base;
    const int by = bid / j.nbx, bx = bid % j.nbx;
    const int rowBase = by * 32, colBase = bx * 64;
    const int t = threadIdx.x, lane = t & 63, wid = t >> 6;
    const int wc = wid;
    const int Kd = j.K, Md = j.M, Nd = j.N;

    const ushort* Bg = j.B + (size_t)(colBase + lane) * Kd;
    int gr = rowBase + (lane & 31); if (gr >= Md) gr = Md - 1;
    const ushort* Ag = j.A + (size_t)gr * Kd + (2 * wid + (lane >> 5)) * 8;

    f32x4 acc[2];
#pragma unroll
    for (int m = 0; m < 2; ++m)
#pragma unroll
        for (int r = 0; r < 4; ++r) acc[m][r] = 0.f;

    auto STAGE = [&](int bf, int tt) {
        const int k0 = tt << 6;
        gll16(Bg + k0 + (2 * wid) * 8,     &Bs[bf][(2 * wid) * 512]);
        gll16(Bg + k0 + (2 * wid + 1) * 8, &Bs[bf][(2 * wid + 1) * 512]);
        gll16(Ag + k0,                     &As[bf][(2 * wid) * 256]);
    };
    auto COMPUTE = [&](int bf) {
#pragma unroll
        for (int kc = 0; kc < 2; ++kc) {
            const int c16 = kc * 4 + (lane >> 4);
            bf16x8 af[2], bfg;
#pragma unroll
            for (int m = 0; m < 2; ++m) {
                const int row = m * 16 + (lane & 15);
                af[m] = *(const bf16x8*)&As[bf][c16 * 256 + row * 8];
            }
            {
                const int rowb = wc * 16 + (lane & 15);
                bfg = *(const bf16x8*)&Bs[bf][c16 * 512 + rowb * 8];
            }
#pragma unroll
            for (int m = 0; m < 2; ++m)
                acc[m] = __builtin_amdgcn_mfma_f32_16x16x32_bf16(af[m], bfg, acc[m], 0, 0, 0);
        }
    };

    const int nt = Kd >> 6;     // >= 8 for all jobs
    STAGE(0, 0); STAGE(1, 1); STAGE(2, 2);
    asm volatile("s_waitcnt vmcnt(6)" ::: "memory");   // tile 0 resident
    __builtin_amdgcn_s_barrier();
    for (int tt = 0; tt < nt; ++tt) {
        if (tt + 3 < nt) STAGE((tt + 3) & 3, tt + 3);
        COMPUTE(tt & 3);
        if (tt < nt - 1) {
            if (tt + 3 < nt)      asm volatile("s_waitcnt vmcnt(6)" ::: "memory");
            else if (tt + 2 < nt) asm volatile("s_waitcnt vmcnt(3)" ::: "memory");
            else                  asm volatile("s_waitcnt vmcnt(0)" ::: "memory");
            __builtin_amdgcn_s_barrier();
        }
    }

    // epilogue: C/D layout col=lane&15, row=(lane>>4)*4+reg  [m89-verified]
    const int cl = lane & 15, rh = lane >> 4;
#pragma unroll
    for (int m = 0; m < 2; ++m) {
        const int col = colBase + wc * 16 + cl;
#pragma unroll
        for (int r = 0; r < 4; ++r) {
            const int rr = rowBase + m * 16 + rh * 4 + r;
            if (rr < Md) {
                float v = acc[m][r];
                if (j.flags & 1) v += j.bias[col];
                if (j.flags & 2) v = fmaxf(v, 0.f);
                if (j.resid) v += j.resid[(size_t)rr * Nd + col];
                if ((j.flags & 4) && col >= 1024) {
                    // V transpose: vext[b][h][d][vv*128 + j] (row stride KEXT)
                    const int cc = col - 1024;               // 0..1023
                    const int hh = (cc >> 6) & 7, d = cc & 63, vv = cc >> 9;
                    const int bb = rr >> 7, jj2 = rr & 127;
                    j.vext[((size_t)((bb * 8 + hh) * 64 + d)) * KEXT + vv * 128 + jj2] = f2bf(v);
                } else {
                    if (j.Cf) j.Cf[(size_t)rr * Nd + col] = v;
                    if (j.Cb) j.Cb[(size_t)rr * Nd + col] = f2bf(v);
                }
            }
        }
    }
}

// ---------------------------------------------------------------------------
// score_gemm: per-layer MFMA scores. K=64 single-step, strided A/B (lda=2048).
//   blocks 0..255   : qk[b,i,h,j]  = Q_h K_h^T   per (b,h)  [f32, [b][i][h][j]]
//   blocks 256..2303: qkk[bi,h,n]  = Q_h kproj_ext_h^T      [f32, [bi][h][1024]]
// ---------------------------------------------------------------------------
__global__ __launch_bounds__(256) void score_gemm(
    const ushort* __restrict__ qkvv, const ushort* __restrict__ kprojl,
    float* __restrict__ qk, float* __restrict__ qkk)
{
    __shared__ ushort As[2048];
    __shared__ ushort Bs[4096];
    const int t = threadIdx.x, lane = t & 63, wid = t >> 6;
    const int bid = blockIdx.x;
    const ushort *Abase, *Bbase;
    float* Cbase; int crs, rowBase, colBase;
    if (bid < 256) {
        const int q = bid >> 3, sub = bid & 7;
        const int b = q >> 3, h = q & 7;
        rowBase = (sub >> 1) * 32; colBase = (sub & 1) * 64;
        Abase = qkvv + (size_t)(b * SS) * LDQ + h * HD;
        Bbase = qkvv + (size_t)(b * SS) * LDQ + 512 + h * HD;
        Cbase = qk + (size_t)b * 131072 + h * 128;
        crs = 1024;
    } else {
        const int idx = bid - 256;
        const int h = idx >> 8, sub = idx & 255;
        rowBase = (sub >> 4) * 32; colBase = (sub & 15) * 64;
        Abase = qkvv + h * HD;
        Bbase = kprojl + h * HD;
        Cbase = qkk + (size_t)h * 1024;
        crs = 8192;
    }
    {
        const ushort* Bg = Bbase + (size_t)(colBase + lane) * LDQ;
        const ushort* Ag = Abase + (size_t)(rowBase + (lane & 31)) * LDQ
                           + (2 * wid + (lane >> 5)) * 8;
        gll16(Bg + (2 * wid) * 8,     &Bs[(2 * wid) * 512]);
        gll16(Bg + (2 * wid + 1) * 8, &Bs[(2 * wid + 1) * 512]);
        gll16(Ag,                     &As[(2 * wid) * 256]);
        asm volatile("s_waitcnt vmcnt(0)" ::: "memory");
        __builtin_amdgcn_s_barrier();
    }
    f32x4 acc[2];
#pragma unroll
    for (int m = 0; m < 2; ++m)
#pragma unroll
        for (int r = 0; r < 4; ++r) acc[m][r] = 0.f;
#pragma unroll
    for (int kc = 0; kc < 2; ++kc) {
        const int c16 = kc * 4 + (lane >> 4);
        bf16x8 af[2], bfg;
#pragma unroll
        for (int m = 0; m < 2; ++m) {
            const int row = m * 16 + (lane & 15);
            af[m] = *(const bf16x8*)&As[c16 * 256 + row * 8];
        }
        {
            const int rowb = wid * 16 + (lane & 15);
            bfg = *(const bf16x8*)&Bs[c16 * 512 + rowb * 8];
        }
#pragma unroll
        for (int m = 0; m < 2; ++m)
            acc[m] = __builtin_amdgcn_mfma_f32_16x16x32_bf16(af[m], bfg, acc[m], 0, 0, 0);
    }
    const int cl = lane & 15, rh = lane >> 4;
#pragma unroll
    for (int m = 0; m < 2; ++m) {
        const int col = colBase + wid * 16 + cl;
        const int row0 = rowBase + m * 16 + rh * 4;
#pragma unroll
        for (int r = 0; r < 4; ++r)
            Cbase[(size_t)(row0 + r) * crs + col] = acc[m][r];
    }
}

// ---------------------------------------------------------------------------
// pv_kernel: fused softmax + PV via MFMA. Per block: (b, h, 16-row i-band).
//   P_ext[i][k] = [attn*sm | attn*om | ap | 0]   built in LDS (chunk-major)
//   B_ext[d][k] = [vs^T | vo^T | pe_v^T | 0]     staged via global_load_lds
//   asum[b,i,h*64+d] = sum_k P_ext[i,k] B_ext[d,k]
// ---------------------------------------------------------------------------
__global__ __launch_bounds__(256) void pv_kernel(
    const ushort* __restrict__ vext, const float* __restrict__ qk,
    const float* __restrict__ qkk,
    const int* __restrict__ know_adj, const int* __restrict__ pos_mask,
    const int* __restrict__ adj, const int* __restrict__ s_mask,
    const int* __restrict__ o_mask, ushort* __restrict__ asum)
{
    __shared__ ushort Ps[40 * PSTR];     // [chunk][16 rows][8] + pad
    __shared__ ushort Bs[40 * 512];      // [chunk][64 rows][8]
    __shared__ float ap[16][11];
    const int blk = blockIdx.x;
    const int ib = blk & 7, h = (blk >> 3) & 7, b = blk >> 6;
    const int t = threadIdx.x, lane = t & 63, wid = t >> 6;

    if (t < 176) ap[t / 11][t % 11] = 0.f;
    __syncthreads();

    // stage all 40 B_ext chunks (async; overlaps P build below)
    {
        const ushort* vbase = vext + ((size_t)((b * 8 + h) * 64) + lane) * KEXT;
#pragma unroll
        for (int s = 0; s < 5; ++s) {
            const int c = s * 8 + wid * 2;
            gll16(vbase + c * 8,       &Bs[c * 512]);
            gll16(vbase + (c + 1) * 8, &Bs[(c + 1) * 512]);
        }
    }

    // P build: row r = t>>4 (16 rows), group g = t&15, j = g*8 + u
    {
        const int r = t >> 4, g = t & 15;
        const int i = ib * 16 + r;
        const int tok = b * 128 + i;
        const float* qkrow  = qk + (size_t)b * 131072 + (size_t)i * 1024 + h * 128 + g * 8;
        const float* qkkrow = qkk + (size_t)tok * 8192 + h * 1024;
        const int base = tok * 128 + g * 8;
        const int pb   = i * 128 + g * 8;
        int4 kn0 = *(const int4*)(know_adj + base), kn1 = *(const int4*)(know_adj + base + 4);
        int4 ad0 = *(const int4*)(adj + base),      ad1 = *(const int4*)(adj + base + 4);
        int4 sm0 = *(const int4*)(s_mask + base),   sm1 = *(const int4*)(s_mask + base + 4);
        int4 om0 = *(const int4*)(o_mask + base),   om1 = *(const int4*)(o_mask + base + 4);
        int4 po0 = *(const int4*)(pos_mask + pb),   po1 = *(const int4*)(pos_mask + pb + 4);
        float4 q0 = *(const float4*)qkrow,          q1 = *(const float4*)(qkrow + 4);
        int kn[8] = {kn0.x, kn0.y, kn0.z, kn0.w, kn1.x, kn1.y, kn1.z, kn1.w};
        int ad[8] = {ad0.x, ad0.y, ad0.z, ad0.w, ad1.x, ad1.y, ad1.z, ad1.w};
        int sm[8] = {sm0.x, sm0.y, sm0.z, sm0.w, sm1.x, sm1.y, sm1.z, sm1.w};
        int om[8] = {om0.x, om0.y, om0.z, om0.w, om1.x, om1.y, om1.z, om1.w};
        int po[8] = {po0.x, po0.y, po0.z, po0.w, po1.x, po1.y, po1.z, po1.w};
        float qv[8] = {q0.x, q0.y, q0.z, q0.w, q1.x, q1.y, q1.z, q1.w};
        float e[8];
        int pcl[8];
        float mx = -3e38f;
#pragma unroll
        for (int u = 0; u < 8; ++u) {
            int p = po[u]; p = p < 0 ? 0 : (p > 10 ? 10 : p);
            pcl[u] = p;
            float sc = (qv[u] + qkkrow[kn[u]] + qkkrow[1000 + p]) * 0.125f;
            if (!ad[u]) sc -= 1e30f;
            e[u] = sc; mx = fmaxf(mx, sc);
        }
        mx = fmaxf(mx, __shfl_xor(mx, 1));
        mx = fmaxf(mx, __shfl_xor(mx, 2));
        mx = fmaxf(mx, __shfl_xor(mx, 4));
        mx = fmaxf(mx, __shfl_xor(mx, 8));
        float sum = 0.f;
#pragma unroll
        for (int u = 0; u < 8; ++u) { e[u] = __expf(e[u] - mx); sum += e[u]; }
        sum += __shfl_xor(sum, 1);
        sum += __shfl_xor(sum, 2);
        sum += __shfl_xor(sum, 4);
        sum += __shfl_xor(sum, 8);
        const float inv = 1.f / sum;
        ushort p1v[8], p2v[8];
#pragma unroll
        for (int u = 0; u < 8; ++u) {
            const float a = e[u] * inv;
            p1v[u] = f2bf(a * (float)sm[u]);
            p2v[u] = f2bf(a * (float)om[u]);
            atomicAdd(&ap[r][pcl[u]], a);
        }
        // chunk g holds k = g*8..g*8+7 (p1); chunk 16+g holds 128+j (p2)
        *(uint4*)&Ps[g * PSTR + r * 8]        = *(uint4*)p1v;
        *(uint4*)&Ps[(16 + g) * PSTR + r * 8] = *(uint4*)p2v;
    }
    __syncthreads();

    // ap -> chunks 32..39 (k = 256..319): 64 slots x 16 rows, 4 per thread
#pragma unroll
    for (int u = 0; u < 4; ++u) {
        const int idx = t * 4 + u;
        const int k = 256 + (idx & 63), rr = idx >> 6;
        const float v = (k < 267) ? ap[rr][k - 256] : 0.f;
        Ps[(k >> 3) * PSTR + rr * 8 + (k & 7)] = f2bf(v);
    }
    __syncthreads();   // drains vmcnt too: B_ext resident, P complete

    f32x4 acc;
#pragma unroll
    for (int r = 0; r < 4; ++r) acc[r] = 0.f;
#pragma unroll
    for (int s = 0; s < 5; ++s) {
#pragma unroll
        for (int kc = 0; kc < 2; ++kc) {
            const int ch = s * 8 + kc * 4 + (lane >> 4);
            bf16x8 af = *(const bf16x8*)&Ps[ch * PSTR + (lane & 15) * 8];
            bf16x8 bfg = *(const bf16x8*)&Bs[ch * 512 + (wid * 16 + (lane & 15)) * 8];
            acc = __builtin_amdgcn_mfma_f32_16x16x32_bf16(af, bfg, acc, 0, 0, 0);
        }
    }
    const int cl = lane & 15, rh = lane >> 4;
    const int col = wid * 16 + cl;           // d
#pragma unroll
    for (int r = 0; r < 4; ++r) {
        const int rowv = rh * 4 + r;         // 0..15
        asum[(size_t)(b * 128 + ib * 16 + rowv) * 512 + h * 64 + col] = f2bf(acc[r]);
    }
}

// ---------------------------------------------------------------------------
// Prep: weights/knowledge/x -> bf16; pe_k rows into kproj_ext; pe_v^T + zero
// pad into vext cols 256..319 (static across layers).
// ---------------------------------------------------------------------------
struct PrepArgs {
    const float *Wq, *Wk, *Wvs, *Wvo, *Wo, *Wkn, *w1, *w2, *know, *x, *pek, *pev;
    ushort *wqkvv, *wo, *wkn, *w1b, *w2b, *knowb, *hb, *kpe, *vext;
    float *h;
};
#define P4_WQKVV 1048576
#define P4_B1 (P4_WQKVV + 262144)          // wo
#define P4_B2 (P4_B1 + 262144)             // wkn
#define P4_B3 (P4_B2 + 1048576)            // w1
#define P4_B4 (P4_B3 + 1048576)            // w2
#define P4_B5 (P4_B4 + 128000)             // knowledge
#define P4_B6 (P4_B5 + 65536)              // x
#define P4_B7 (P4_B6 + 5632)               // pe_k -> kproj_ext rows
#define P4_TOT (P4_B7 + 32768)             // pe_v^T -> vext cols 256..319

__global__ __launch_bounds__(256) void prep_kernel(PrepArgs pa)
{
    const int i = blockIdx.x * 256 + threadIdx.x;
    if (i >= P4_TOT) return;
    if (i >= P4_B7) {              // pe_v^T + zero pad into vext
        const int k = i - P4_B7;   // 0..32767
        const int bh = k >> 10, r2 = k & 1023, d = r2 >> 4, s4 = r2 & 15;
        ushort o[4];
#pragma unroll
        for (int c = 0; c < 4; ++c) {
            const int p = s4 * 4 + c;
            o[c] = (p < 11) ? f2bf(pa.pev[p * 64 + d]) : (ushort)0;
        }
        *(ushort4*)(pa.vext + ((size_t)(bh * 64 + d)) * KEXT + 256 + s4 * 4)
            = *(ushort4*)o;
        return;
    }
    const float4* src;
    ushort4* dst;
    if (i < P4_WQKVV) {           // [L][4*512][512]: per-layer concat Wq|Wk|Wvs|Wvo
        const int l = i >> 18, r = i & 262143, q = r >> 16;
        const float* s = (q == 0 ? pa.Wq : q == 1 ? pa.Wk : q == 2 ? pa.Wvs : pa.Wvo);
        src = (const float4*)s + l * 65536 + (r & 65535);
        dst = (ushort4*)pa.wqkvv + i;
    } else if (i < P4_B1) {
        const int k = i - P4_WQKVV;
        src = (const float4*)pa.Wo + k; dst = (ushort4*)pa.wo + k;
    } else if (i < P4_B2) {
        const int k = i - P4_B1;
        src = (const float4*)pa.Wkn + k; dst = (ushort4*)pa.wkn + k;
    } else if (i < P4_B3) {
        const int k = i - P4_B2;
        src = (const float4*)pa.w1 + k; dst = (ushort4*)pa.w1b + k;
    } else if (i < P4_B4) {
        const int k = i - P4_B3;
        src = (const float4*)pa.w2 + k; dst = (ushort4*)pa.w2b + k;
    } else if (i < P4_B5) {
        const int k = i - P4_B4;
        src = (const float4*)pa.know + k; dst = (ushort4*)pa.knowb + k;
    } else if (i < P4_B6) {
        const int k = i - P4_B5;
        src = (const float4*)pa.x + k; dst = (ushort4*)pa.hb + k;
        ((float4*)pa.h)[k] = *src;
    } else {                       // pe_k replicate: row 1000+p, col c in [0,2048)
        const int k = i - P4_B6;   // 0..5631
        const int c4 = k * 4;
        const int p = c4 >> 11, col = c4 & 2047, d = col & 63;
        src = (const float4*)(pa.pek + p * 64 + d);
        dst = (ushort4*)(pa.kpe + (size_t)(1000 + p) * 2048 + col);
    }
    float4 v = *src;
    ushort4 o; o.x = f2bf(v.x); o.y = f2bf(v.y); o.z = f2bf(v.z); o.w = f2bf(v.w);
    *dst = o;
}

// ---------------------------------------------------------------------------
// LayerNorm rows of 512 (fp32 in), writes fp32 Yf and bf16 Yb.
// ---------------------------------------------------------------------------
__global__ __launch_bounds__(256) void ln_kernel(
    const float* __restrict__ X, const float* __restrict__ g,
    const float* __restrict__ bt, float* __restrict__ Yf,
    ushort* __restrict__ Yb, int rows)
{
    const int w = threadIdx.x >> 6, lane = threadIdx.x & 63;
    const int row = blockIdx.x * 4 + w;
    if (row >= rows) return;
    const float* x = X + (size_t)row * EE;
    float4 v0 = ((const float4*)x)[lane];
    float4 v1 = ((const float4*)x)[lane + 64];
    float s  = v0.x + v0.y + v0.z + v0.w + v1.x + v1.y + v1.z + v1.w;
    float q2 = v0.x*v0.x + v0.y*v0.y + v0.z*v0.z + v0.w*v0.w
             + v1.x*v1.x + v1.y*v1.y + v1.z*v1.z + v1.w*v1.w;
#pragma unroll
    for (int o = 32; o; o >>= 1) { s += __shfl_xor(s, o); q2 += __shfl_xor(q2, o); }
    const float mean = s * (1.f / EE);
    const float var  = q2 * (1.f / EE) - mean * mean;
    const float rstd = rsqrtf(var + 1e-5f);
    float4 g0 = ((const float4*)g)[lane],  g1 = ((const float4*)g)[lane + 64];
    float4 b0 = ((const float4*)bt)[lane], b1 = ((const float4*)bt)[lane + 64];
    float4 o0, o1;
    o0.x = (v0.x - mean) * rstd * g0.x + b0.x;
    o0.y = (v0.y - mean) * rstd * g0.y + b0.y;
    o0.z = (v0.z - mean) * rstd * g0.z + b0.z;
    o0.w = (v0.w - mean) * rstd * g0.w + b0.w;
    o1.x = (v1.x - mean) * rstd * g1.x + b1.x;
    o1.y = (v1.y - mean) * rstd * g1.y + b1.y;
    o1.z = (v1.z - mean) * rstd * g1.z + b1.z;
    o1.w = (v1.w - mean) * rstd * g1.w + b1.w;
    float* y = Yf + (size_t)row * EE;
    ((float4*)y)[lane] = o0;
    ((float4*)y)[lane + 64] = o1;
    ushort* yb = Yb + (size_t)row * EE;
    ushort4 p0, p1;
    p0.x = f2bf(o0.x); p0.y = f2bf(o0.y); p0.z = f2bf(o0.z); p0.w = f2bf(o0.w);
    p1.x = f2bf(o1.x); p1.y = f2bf(o1.y); p1.z = f2bf(o1.z); p1.w = f2bf(o1.w);
    ((ushort4*)yb)[lane] = p0;
    ((ushort4*)yb)[lane + 64] = p1;
}

// ---------------------------------------------------------------------------
extern "C" void kernel_launch(void* const* d_in, const int* in_sizes, int n_in,
                              void* d_out, int out_size, void* d_ws, size_t ws_size,
                              hipStream_t stream)
{
    const float* x         = (const float*)d_in[0];
    const int*   adj       = (const int*)d_in[1];
    const int*   s_mask    = (const int*)d_in[2];
    const int*   o_mask    = (const int*)d_in[3];
    const float* knowledge = (const float*)d_in[4];
    const int*   know_adj  = (const int*)d_in[5];
    const int*   pos_mask  = (const int*)d_in[6];
    const float* pe_k      = (const float*)d_in[7];
    const float* pe_v      = (const float*)d_in[8];
    const float* Wq        = (const float*)d_in[9];
    const float* Wk        = (const float*)d_in[10];
    const float* Wvs       = (const float*)d_in[11];
    const float* Wvo       = (const float*)d_in[12];
    const float* Wo        = (const float*)d_in[13];
    const float* Wkn       = (const float*)d_in[14];
    const float* ln1_g     = (const float*)d_in[15];
    const float* ln1_b     = (const float*)d_in[16];
    const float* w1        = (const float*)d_in[17];
    const float* b1        = (const float*)d_in[18];
    const float* w2        = (const float*)d_in[19];
    const float* b2        = (const float*)d_in[20];
    const float* ln2_g     = (const float*)d_in[21];
    const float* ln2_b     = (const float*)d_in[22];

    const int NTOK = BB * SS;                 // 512
    const size_t NTE = (size_t)NTOK * EE;     // 262144

    // workspace layout
    float*  h      = (float*)d_ws;                     // 1 MB
    float*  xt     = h + NTE;                          // 1 MB
    float*  qk     = xt + NTE;                         // [b][i][h][j] 2 MB
    float*  qkk    = qk + (size_t)NTOK * 1024;         // [bi][h][1024] 16 MB
    ushort* hb     = (ushort*)(qkk + (size_t)NTOK * 8192);  // 512 KB
    ushort* qkvv   = hb + NTE;                         // 2 MB
    ushort* kprojb = qkvv + (size_t)NTOK * LDQ;        // [1024][2048] 4 MB
    ushort* asumb  = kprojb + (size_t)1024 * LDQ;      // 512 KB
    ushort* ffnb   = asumb + NTE;                      // 2 MB
    ushort* wqkvv  = ffnb + (size_t)NTOK * FFD;        // 8 MB
    ushort* wob    = wqkvv + (size_t)NL * 4 * EE * EE; // 2 MB
    ushort* wknb   = wob + (size_t)NL * EE * EE;       // 2 MB
    ushort* w1b    = wknb + (size_t)NL * EE * EE;      // 8 MB
    ushort* w2b    = w1b + (size_t)NL * FFD * EE;      // 8 MB
    ushort* knowb  = w2b + (size_t)NL * EE * FFD;      // 1 MB
    ushort* vextb  = knowb + (size_t)1000 * EE;        // [32][64][320] 1.3 MB

    PrepArgs pa;
    pa.Wq = Wq; pa.Wk = Wk; pa.Wvs = Wvs; pa.Wvo = Wvo; pa.Wo = Wo; pa.Wkn = Wkn;
    pa.w1 = w1; pa.w2 = w2; pa.know = knowledge; pa.x = x; pa.pek = pe_k; pa.pev = pe_v;
    pa.wqkvv = wqkvv; pa.wo = wob; pa.wkn = wknb; pa.w1b = w1b; pa.w2b = w2b;
    pa.knowb = knowb; pa.hb = hb; pa.h = h; pa.kpe = kprojb; pa.vext = vextb;
    prep_kernel<<<dim3((P4_TOT + 255) / 256), dim3(256), 0, stream>>>(pa);

    const dim3 blk(256);
    for (int l = 0; l < NL; ++l) {
        GemmJob jq{};   // QKVV concat: [512,2048] = h @ Wqkvv_l^T; V -> vext
        jq.A = hb; jq.B = wqkvv + (size_t)l * 4 * EE * EE;
        jq.Cb = qkvv; jq.vext = vextb; jq.flags = 4;
        jq.M = NTOK; jq.N = 4 * EE; jq.K = EE;
        jq.nbx = 32; jq.base = 0;
        if (l == 0) {
            GemmJob jk{};   // all-layers kproj: [1000, 2048] = know @ Wkn_stk^T
            jk.A = knowb; jk.B = wknb;
            jk.Cb = kprojb; jk.M = 1000; jk.N = NL * EE; jk.K = EE;
            jk.nbx = 32; jk.base = 512;
            gemm_bf16<<<dim3(512 + 1024), blk, 0, stream>>>(jq, jk, 2);
        } else {
            gemm_bf16<<<dim3(512), blk, 0, stream>>>(jq, jq, 1);
        }

        score_gemm<<<dim3(2304), blk, 0, stream>>>(qkvv, kprojb + (size_t)l * EE,
                                                   qk, qkk);

        pv_kernel<<<dim3(256), blk, 0, stream>>>(vextb, qk, qkk, know_adj, pos_mask,
                                                 adj, s_mask, o_mask, asumb);

        GemmJob jo{};   // Wo: xt = asum @ Wo_l^T + h   (128 blocks)
        jo.A = asumb; jo.B = wob + (size_t)l * EE * EE;
        jo.Cf = xt; jo.resid = h; jo.M = NTOK; jo.N = EE; jo.K = EE;
        jo.nbx = 8; jo.base = 0;
        gemm_bf16<<<dim3(128), blk, 0, stream>>>(jo, jo, 1);

        ln_kernel<<<dim3(128), blk, 0, stream>>>(xt, ln1_g + l * EE, ln1_b + l * EE,
                                                 h, hb, NTOK);

        GemmJob jf1{};  // FFN1: relu(h @ w1_l^T + b1) -> bf16   (512 blocks)
        jf1.A = hb; jf1.B = w1b + (size_t)l * FFD * EE;
        jf1.Cb = ffnb; jf1.bias = b1 + (size_t)l * FFD; jf1.flags = 3;
        jf1.M = NTOK; jf1.N = FFD; jf1.K = EE; jf1.nbx = 32; jf1.base = 0;
        gemm_bf16<<<dim3(512), blk, 0, stream>>>(jf1, jf1, 1);

        GemmJob jf2{};  // FFN2: xt = ffn @ w2_l^T + b2 + h   (128 blocks)
        jf2.A = ffnb; jf2.B = w2b + (size_t)l * EE * FFD;
        jf2.Cf = xt; jf2.bias = b2 + (size_t)l * EE; jf2.resid = h; jf2.flags = 1;
        jf2.M = NTOK; jf2.N = EE; jf2.K = FFD; jf2.nbx = 8; jf2.base = 0;
        gemm_bf16<<<dim3(128), blk, 0, stream>>>(jf2, jf2, 1);

        float* lnout = (l == NL - 1) ? (float*)d_out : h;
        ln_kernel<<<dim3(128), blk, 0, stream>>>(xt, ln2_g + l * EE, ln2_b + l * EE,
                                                 lnout, hb, NTOK);
    }
}